// Round 10
// baseline (488.497 us; speedup 1.0000x reference)
//
#include <hip/hip_runtime.h>
#include <math.h>

// GNNBlock: global-LN -> relu*dropout -> SAGE mean-aggr (CSR pull, bf16) -> dual linear via MFMA
// N=50000, E=800000, D=128
#define N_NODES 50000
#define N_EDGES 800000
#define D 128
#define EPS 1e-5f

// ---------------- workspace layout ----------------
// [0]        double sum, double sumsq        (16 B)
// [16]       int cursor                      (4 B)
// [64]       int   deg[N]                    (200000 B)
// [200192]   int   offs[N]                   (200000 B)   start; mutated to "end" by fill
// [400448]   int   bucket[E]                 (3.2 MB)     src indices grouped by dst
// [3600448]  ushort w16t[2][2][128][128]     (128 KB)     [wl/wr][hi/lo][out][k] bf16, transposed
// [3731520]  ushort agg16[N*D]               (12.8 MB)    mean aggregation, bf16
// [16531520] ushort h16[N*D]                 (12.8 MB)    h = relu(LN(x))*mask, bf16
#define WS_STATS_OFF   0
#define WS_CUR_OFF     16
#define WS_DEG_OFF     64
#define WS_OFFS_OFF    200192
#define WS_BUCKET_OFF  400448
#define WS_W16T_OFF    3600448
#define WS_AGG_OFF     3731520
#define WS_H_OFF       16531520
#define WS_ZERO_BYTES  200192     // stats + cursor + deg

#define RED_BLOCKS 1024
#define DEG_BLOCKS ((N_EDGES + 255) / 256)   // 3125
#define H_BLOCKS   2048
#define FILL_BLOCKS DEG_BLOCKS

#define MM_BLOCKS 256
#define MM_SLOTS  (MM_BLOCKS * 8)            // 2048 wave slots
#define MM_TILES  (N_NODES / 16)             // 3125 node tiles (exact)

typedef __attribute__((ext_vector_type(8))) short short8v;   // 8 bf16 = 4 VGPR (MFMA A/B frag)
typedef __attribute__((ext_vector_type(4))) float f32x4;     // MFMA C/D frag

// bf16 helpers (RNE encode, shift decode)
static __device__ inline unsigned short f2bf(float f) {
    unsigned u = __float_as_uint(f);
    return (unsigned short)((u + 0x7FFFu + ((u >> 16) & 1u)) >> 16);
}
static __device__ inline float bf2f(unsigned short s) {
    return __uint_as_float(((unsigned)s) << 16);
}

// ---------------- kernel 1: global sum/sumsq + degree histogram (fused, independent) ----------------
__global__ __launch_bounds__(256) void k_pre(const float* __restrict__ x,
                                             const int* __restrict__ ei,
                                             double* __restrict__ stats,
                                             int* __restrict__ deg,
                                             int total4) {
    __shared__ float bs[4], bss[4];
    if (blockIdx.x < RED_BLOCKS) {
        int tid = blockIdx.x * 256 + threadIdx.x;
        int stride = RED_BLOCKS * 256;
        float s = 0.f, ss = 0.f;
        for (int i = tid; i < total4; i += stride) {
            float4 v = ((const float4*)x)[i];
            s  += v.x + v.y + v.z + v.w;
            ss += v.x*v.x + v.y*v.y + v.z*v.z + v.w*v.w;
        }
        for (int off = 32; off; off >>= 1) {
            s  += __shfl_down(s, off);
            ss += __shfl_down(ss, off);
        }
        int lane = threadIdx.x & 63, wid = threadIdx.x >> 6;
        if (lane == 0) { bs[wid] = s; bss[wid] = ss; }
        __syncthreads();
        if (threadIdx.x == 0) {
            float t = 0.f, tt = 0.f;
            for (int w = 0; w < 4; ++w) { t += bs[w]; tt += bss[w]; }
            atomicAdd(stats, (double)t);
            atomicAdd(stats + 1, (double)tt);
        }
    } else {
        int e = (blockIdx.x - RED_BLOCKS) * 256 + threadIdx.x;
        if (e < N_EDGES) atomicAdd(deg + ei[N_EDGES + e], 1);
    }
}

// ---------------- kernel 1b: weight prep — transpose + hi/lo bf16 split ----------------
// w16t[p][s][o][k]: s=0 hi=bf16(w), s=1 lo=bf16(w - hi). A@(hi+lo) ~= A@w at f32 weight precision.
__global__ __launch_bounds__(256) void k_wprep(const float* __restrict__ w_l,
                                               const float* __restrict__ w_r,
                                               unsigned short* __restrict__ w16t) {
    int t = blockIdx.x * 256 + threadIdx.x;          // 8192 threads: [p][o][k4]
    int p = t >> 12;
    int o = (t >> 5) & 127;
    int k4 = t & 31;
    const float* w = p ? w_r : w_l;
    ushort4 hi, lo;
    float v0 = w[(k4 * 4 + 0) * D + o];
    float v1 = w[(k4 * 4 + 1) * D + o];
    float v2 = w[(k4 * 4 + 2) * D + o];
    float v3 = w[(k4 * 4 + 3) * D + o];
    hi.x = f2bf(v0); lo.x = f2bf(v0 - bf2f(hi.x));
    hi.y = f2bf(v1); lo.y = f2bf(v1 - bf2f(hi.y));
    hi.z = f2bf(v2); lo.z = f2bf(v2 - bf2f(hi.z));
    hi.w = f2bf(v3); lo.w = f2bf(v3 - bf2f(hi.w));
    *(ushort4*)(w16t + p * 32768 + o * D + k4 * 4) = hi;
    *(ushort4*)(w16t + p * 32768 + 16384 + o * D + k4 * 4) = lo;
}

// ---------------- kernel 2: bucket-region assignment (block scan + global cursor) ----------------
__global__ __launch_bounds__(256) void k_offs(const int* __restrict__ deg,
                                              int* __restrict__ offs,
                                              int* __restrict__ cursor) {
    __shared__ int sc[256];
    __shared__ int sbase;
    int t = threadIdx.x;
    int n = blockIdx.x * 256 + t;
    int d = (n < N_NODES) ? deg[n] : 0;
    sc[t] = d;
    __syncthreads();
    for (int off = 1; off < 256; off <<= 1) {   // inclusive Hillis-Steele scan
        int u = (t >= off) ? sc[t - off] : 0;
        __syncthreads();
        sc[t] += u;
        __syncthreads();
    }
    int incl = sc[t];
    if (t == 255) sbase = atomicAdd(cursor, incl);
    __syncthreads();
    if (n < N_NODES) offs[n] = sbase + (incl - d);
}

// ---------------- kernel 3: h16 = bf16(relu(LN(x))*mask)  +  bucket fill (fused) ----------------
__global__ __launch_bounds__(256) void k_hfill(const float* __restrict__ x,
                                               const float* __restrict__ mask,
                                               const float* __restrict__ lnw,
                                               const float* __restrict__ lnb,
                                               const double* __restrict__ stats,
                                               const int* __restrict__ ei,
                                               int* __restrict__ offs,
                                               int* __restrict__ bucket,
                                               unsigned short* __restrict__ h16,
                                               int total4) {
    if (blockIdx.x < H_BLOCKS) {
        double M = (double)N_NODES * (double)D;
        double mean_d = stats[0] / M;
        double var = stats[1] / M - mean_d * mean_d;
        if (var < 0.0) var = 0.0;
        float mean = (float)mean_d;
        float rstd = (float)(1.0 / (sqrt(var) + (double)EPS));
        int tid = blockIdx.x * 256 + threadIdx.x;
        int stride = H_BLOCKS * 256;
        for (int i = tid; i < total4; i += stride) {
            float4 v = ((const float4*)x)[i];
            float4 m = ((const float4*)mask)[i];
            int c4 = i & (D / 4 - 1);
            float4 w = ((const float4*)lnw)[c4];
            float4 b = ((const float4*)lnb)[c4];
            float4 r;
            r.x = fmaxf((v.x - mean) * rstd * w.x + b.x, 0.f) * m.x;
            r.y = fmaxf((v.y - mean) * rstd * w.y + b.y, 0.f) * m.y;
            r.z = fmaxf((v.z - mean) * rstd * w.z + b.z, 0.f) * m.z;
            r.w = fmaxf((v.w - mean) * rstd * w.w + b.w, 0.f) * m.w;
            ushort4 o;
            o.x = f2bf(r.x); o.y = f2bf(r.y); o.z = f2bf(r.z); o.w = f2bf(r.w);
            ((ushort4*)h16)[i] = o;
        }
    } else {
        int e = (blockIdx.x - H_BLOCKS) * 256 + threadIdx.x;
        if (e < N_EDGES) {
            int dst = ei[N_EDGES + e];
            int p = atomicAdd(offs + dst, 1);
            bucket[p] = ei[e];
        }
    }
}

// ---------------- kernel 4: pull aggregation (atomic-free, bf16 in/out) ----------------
// 32 lanes per dst node, 4 bf16 channels (8B) per lane; f32 accumulate, bf16 store.
__global__ __launch_bounds__(256) void k_agg(const int* __restrict__ bucket,
                                             const int* __restrict__ offs,
                                             const int* __restrict__ deg,
                                             const unsigned short* __restrict__ h16,
                                             unsigned short* __restrict__ agg16) {
    int t = blockIdx.x * blockDim.x + threadIdx.x;
    int node = t >> 5;
    if (node >= N_NODES) return;
    int c = t & 31;
    int dg = deg[node];
    int end = offs[node];          // post-fill value = bucket end
    int start = end - dg;
    float4 acc = {0.f, 0.f, 0.f, 0.f};
    for (int j = start; j < end; ++j) {
        int src = bucket[j];
        uint2 u = *(const uint2*)(h16 + (long long)src * D + c * 4);
        acc.x += __uint_as_float(u.x << 16);
        acc.y += __uint_as_float(u.x & 0xFFFF0000u);
        acc.z += __uint_as_float(u.y << 16);
        acc.w += __uint_as_float(u.y & 0xFFFF0000u);
    }
    float inv = 1.0f / fmaxf((float)dg, 1.0f);
    ushort4 o;
    o.x = f2bf(acc.x * inv); o.y = f2bf(acc.y * inv);
    o.z = f2bf(acc.z * inv); o.w = f2bf(acc.w * inv);
    *(ushort4*)(agg16 + (long long)node * D + c * 4) = o;
}

// ---------------- kernel 5: MFMA dual matvec with LDS-staged weights ----------------
// 256 blocks x 512 thr (8 waves) = 2048 wave slots; wave handles node-tiles
// {slot, slot+2048} (2nd if <3125) x ALL 8 out-tiles (A-frag feeds 16 MFMA;
// B-frag shared across 2 tiles -> 4 MFMA per ds_read_b128).
// Per phase (agg@w_l then h@w_r): stage that weight's hi+lo (64 KB) into LDS,
// XOR-swizzled (byte ^= (row&7)<<4) so 16-row x 256B-stride frag reads are
// ~2-way conflict (free) instead of 16-way. Kills the 400 MB L3 B-re-read
// traffic that limited round 8 (25000 waves x 16KB global B-frags).
// A/B/C index math identical to round-8 kernel (HW-verified pass).
__global__ __launch_bounds__(512, 2) void k_mmf(const unsigned short* __restrict__ agg16,
                                                const unsigned short* __restrict__ h16,
                                                const unsigned short* __restrict__ w16t,
                                                const float* __restrict__ b_l,
                                                float* __restrict__ out) {
    __shared__ uint4 lds4[4096];                 // 64 KB: [hi|lo][128 out][128 k] bf16, swizzled
    unsigned char* ldsb = (unsigned char*)lds4;
    int tid  = threadIdx.x;
    int wave = tid >> 6;
    int lane = tid & 63;
    int rc = lane & 15;                          // A-row / B-col / D-col
    int kg = lane >> 4;                          // k-group 0..3
    int slot = blockIdx.x * 8 + wave;            // 0..2047 < 3125: always a valid tile
    int nt0 = slot;
    int nt1 = slot + MM_SLOTS;
    bool has1 = (nt1 < MM_TILES);
    int sx = (rc & 7) << 4;                      // read-side swizzle

    f32x4 acc0[8], acc1[8];
#pragma unroll
    for (int ot = 0; ot < 8; ++ot) { acc0[ot] = {0.f,0.f,0.f,0.f}; acc1[ot] = {0.f,0.f,0.f,0.f}; }

#pragma unroll
    for (int phase = 0; phase < 2; ++phase) {
        if (phase) __syncthreads();              // all waves done reading prev stage
        // stage 64 KB (hi+lo of this phase's weight), swizzled
        {
            const uint4* src = (const uint4*)(w16t + phase * 32768);
#pragma unroll
            for (int i = 0; i < 8; ++i) {
                int idx = i * 512 + tid;                       // 16B chunk index, 0..4095
                int byteoff = idx * 16;
                int swz = byteoff ^ (((idx >> 4) & 7) << 4);   // row = idx>>4
                *(uint4*)(ldsb + swz) = src[idx];
            }
        }
        __syncthreads();

        const unsigned short* abase = phase ? h16 : agg16;
        const unsigned short* pa0 = abase + (long long)(nt0 * 16 + rc) * D + kg * 8;
        const unsigned short* pa1 = abase + (long long)((has1 ? nt1 : nt0) * 16 + rc) * D + kg * 8;

#pragma unroll
        for (int k0 = 0; k0 < 4; ++k0) {
            short8v a0 = *(const short8v*)(pa0 + k0 * 32);
            short8v a1 = *(const short8v*)(pa1 + k0 * 32);
#pragma unroll
            for (int ot = 0; ot < 8; ++ot) {
                int bo = (ot * 16 + rc) * 256 + kg * 16 + k0 * 64;
                short8v bhi = *(const short8v*)(ldsb + (bo ^ sx));
                short8v blo = *(const short8v*)(ldsb + ((bo + 32768) ^ sx));
                acc0[ot] = __builtin_amdgcn_mfma_f32_16x16x32_bf16(a0, bhi, acc0[ot], 0, 0, 0);
                acc0[ot] = __builtin_amdgcn_mfma_f32_16x16x32_bf16(a0, blo, acc0[ot], 0, 0, 0);
                if (has1) {
                    acc1[ot] = __builtin_amdgcn_mfma_f32_16x16x32_bf16(a1, bhi, acc1[ot], 0, 0, 0);
                    acc1[ot] = __builtin_amdgcn_mfma_f32_16x16x32_bf16(a1, blo, acc1[ot], 0, 0, 0);
                }
            }
        }
    }

    // epilogue: D col=lane&15, row=(lane>>4)*4+r (HW-verified in round 8)
#pragma unroll
    for (int ot = 0; ot < 8; ++ot) {
        float bias = b_l[ot * 16 + rc];
        float* op0 = out + (long long)(nt0 * 16 + kg * 4) * D + ot * 16 + rc;
#pragma unroll
        for (int r = 0; r < 4; ++r) op0[(long long)r * D] = acc0[ot][r] + bias;
        if (has1) {
            float* op1 = out + (long long)(nt1 * 16 + kg * 4) * D + ot * 16 + rc;
#pragma unroll
            for (int r = 0; r < 4; ++r) op1[(long long)r * D] = acc1[ot][r] + bias;
        }
    }
}

// ---------------- launcher ----------------
extern "C" void kernel_launch(void* const* d_in, const int* in_sizes, int n_in,
                              void* d_out, int out_size, void* d_ws, size_t ws_size,
                              hipStream_t stream) {
    const float* x    = (const float*)d_in[0];
    const int*   ei   = (const int*)d_in[1];
    const float* mask = (const float*)d_in[2];
    const float* lnw  = (const float*)d_in[3];
    const float* lnb  = (const float*)d_in[4];
    const float* w_l  = (const float*)d_in[5];
    const float* b_l  = (const float*)d_in[6];
    const float* w_r  = (const float*)d_in[7];
    float* out = (float*)d_out;

    char* ws = (char*)d_ws;
    double* stats = (double*)(ws + WS_STATS_OFF);
    int*    cursor= (int*)(ws + WS_CUR_OFF);
    int*    deg   = (int*)(ws + WS_DEG_OFF);
    int*    offs  = (int*)(ws + WS_OFFS_OFF);
    int*    bucket= (int*)(ws + WS_BUCKET_OFF);
    unsigned short* w16t  = (unsigned short*)(ws + WS_W16T_OFF);
    unsigned short* agg16 = (unsigned short*)(ws + WS_AGG_OFF);
    unsigned short* h16   = (unsigned short*)(ws + WS_H_OFF);

    // zero stats + cursor + deg (ws is poisoned 0xAA before every launch)
    hipMemsetAsync(d_ws, 0, WS_ZERO_BYTES, stream);

    int total4 = N_NODES * D / 4;
    k_pre<<<RED_BLOCKS + DEG_BLOCKS, 256, 0, stream>>>(x, ei, stats, deg, total4);
    k_wprep<<<32, 256, 0, stream>>>(w_l, w_r, w16t);
    k_offs<<<(N_NODES + 255) / 256, 256, 0, stream>>>(deg, offs, cursor);
    k_hfill<<<H_BLOCKS + FILL_BLOCKS, 256, 0, stream>>>(x, mask, lnw, lnb, stats,
                                                        ei, offs, bucket, h16, total4);
    int ablocks = (N_NODES * 32 + 255) / 256;   // 6250
    k_agg<<<ablocks, 256, 0, stream>>>(bucket, offs, deg, h16, agg16);
    k_mmf<<<MM_BLOCKS, 512, 0, stream>>>(agg16, h16, w16t, b_l, out);
}

// Round 12
// 284.733 us; speedup vs baseline: 1.7156x; 1.7156x over previous
//
#include <hip/hip_runtime.h>
#include <math.h>

// GNNBlock: global-LN -> relu*dropout -> SAGE mean-aggr (CSR pull, bf16) -> dual linear via MFMA
// N=50000, E=800000, D=128
#define N_NODES 50000
#define N_EDGES 800000
#define D 128
#define EPS 1e-5f

// ---------------- workspace layout ----------------
// [0]        double sum, double sumsq        (16 B)
// [16]       int cursor                      (4 B)
// [64]       int   deg[N]                    (200000 B)
// [200192]   int   offs[N]                   (200000 B)   start; mutated to "end" by fill
// [400448]   int   bucket[E]                 (3.2 MB)     src indices grouped by dst
// [3600448]  ushort w16f[2][2][8][4][64][8]  (128 KB)     MFMA B-frags, lane-ordered:
//                                                         [phase][hi/lo][ot][k0][lane][8]
// [3731520]  ushort agg16[N*D]               (12.8 MB)    mean aggregation, bf16
// [16531520] ushort h16[N*D]                 (12.8 MB)    h = relu(LN(x))*mask, bf16
#define WS_STATS_OFF   0
#define WS_CUR_OFF     16
#define WS_DEG_OFF     64
#define WS_OFFS_OFF    200192
#define WS_BUCKET_OFF  400448
#define WS_W16F_OFF    3600448
#define WS_AGG_OFF     3731520
#define WS_H_OFF       16531520
#define WS_ZERO_BYTES  200192     // stats + cursor + deg

#define RED_BLOCKS 1024
#define DEG_BLOCKS ((N_EDGES + 255) / 256)   // 3125
#define H_BLOCKS   2048
#define FILL_BLOCKS DEG_BLOCKS

#define MM_TILES  (N_NODES / 16)             // 3125 node tiles (exact)
#define MM_BLOCKS ((MM_TILES + 7) / 8)       // 391 blocks x 8 waves

typedef __attribute__((ext_vector_type(8))) short short8v;   // 8 bf16 = 4 VGPR (MFMA A/B frag)
typedef __attribute__((ext_vector_type(4))) float f32x4;     // MFMA C/D frag

// bf16 helpers (RNE encode, shift decode)
static __device__ inline unsigned short f2bf(float f) {
    unsigned u = __float_as_uint(f);
    return (unsigned short)((u + 0x7FFFu + ((u >> 16) & 1u)) >> 16);
}
static __device__ inline float bf2f(unsigned short s) {
    return __uint_as_float(((unsigned)s) << 16);
}

// ---------------- kernel 1: global sum/sumsq + degree histogram (fused, independent) ----------------
__global__ __launch_bounds__(256) void k_pre(const float* __restrict__ x,
                                             const int* __restrict__ ei,
                                             double* __restrict__ stats,
                                             int* __restrict__ deg,
                                             int total4) {
    __shared__ float bs[4], bss[4];
    if (blockIdx.x < RED_BLOCKS) {
        int tid = blockIdx.x * 256 + threadIdx.x;
        int stride = RED_BLOCKS * 256;
        float s = 0.f, ss = 0.f;
        for (int i = tid; i < total4; i += stride) {
            float4 v = ((const float4*)x)[i];
            s  += v.x + v.y + v.z + v.w;
            ss += v.x*v.x + v.y*v.y + v.z*v.z + v.w*v.w;
        }
        for (int off = 32; off; off >>= 1) {
            s  += __shfl_down(s, off);
            ss += __shfl_down(ss, off);
        }
        int lane = threadIdx.x & 63, wid = threadIdx.x >> 6;
        if (lane == 0) { bs[wid] = s; bss[wid] = ss; }
        __syncthreads();
        if (threadIdx.x == 0) {
            float t = 0.f, tt = 0.f;
            for (int w = 0; w < 4; ++w) { t += bs[w]; tt += bss[w]; }
            atomicAdd(stats, (double)t);
            atomicAdd(stats + 1, (double)tt);
        }
    } else {
        int e = (blockIdx.x - RED_BLOCKS) * 256 + threadIdx.x;
        if (e < N_EDGES) atomicAdd(deg + ei[N_EDGES + e], 1);
    }
}

// ---------------- kernel 1b: weight prep — hi/lo bf16 split in MFMA-fragment order ----------------
// Output frag(phase, s, ot, k0) = 64 lanes x 8 bf16, lane-major contiguous (1 KB):
//   lane -> rc=lane&15 (B-col o=ot*16+rc), kg=lane>>4; elements k=k0*32+kg*8+j, j=0..7.
// So k_mmf's LDS reads are ds_read_b128 at (frag*1024 + lane*16): linear, conflict-free.
__global__ __launch_bounds__(256) void k_wprep(const float* __restrict__ w_l,
                                               const float* __restrict__ w_r,
                                               unsigned short* __restrict__ w16f) {
    int t = blockIdx.x * 256 + threadIdx.x;      // 4096 threads: [p][ot][k0][lane]
    int p    = t >> 11;
    int ot   = (t >> 8) & 7;
    int k0   = (t >> 6) & 3;
    int lane = t & 63;
    int rc = lane & 15, kg = lane >> 4;
    const float* w = p ? w_r : w_l;
    int o = ot * 16 + rc;
    unsigned short hi[8], lo[8];
#pragma unroll
    for (int j = 0; j < 8; ++j) {
        float v = w[(k0 * 32 + kg * 8 + j) * D + o];
        hi[j] = f2bf(v);
        lo[j] = f2bf(v - bf2f(hi[j]));
    }
    // frag index within phase: s*32 + ot*4 + k0; each frag 512 ushorts
    long long base_hi = ((long long)p * 64 + 0 * 32 + ot * 4 + k0) * 512 + lane * 8;
    long long base_lo = ((long long)p * 64 + 1 * 32 + ot * 4 + k0) * 512 + lane * 8;
    uint4 uhi, ulo;
    uhi.x = (unsigned)hi[0] | ((unsigned)hi[1] << 16);
    uhi.y = (unsigned)hi[2] | ((unsigned)hi[3] << 16);
    uhi.z = (unsigned)hi[4] | ((unsigned)hi[5] << 16);
    uhi.w = (unsigned)hi[6] | ((unsigned)hi[7] << 16);
    ulo.x = (unsigned)lo[0] | ((unsigned)lo[1] << 16);
    ulo.y = (unsigned)lo[2] | ((unsigned)lo[3] << 16);
    ulo.z = (unsigned)lo[4] | ((unsigned)lo[5] << 16);
    ulo.w = (unsigned)lo[6] | ((unsigned)lo[7] << 16);
    *(uint4*)(w16f + base_hi) = uhi;
    *(uint4*)(w16f + base_lo) = ulo;
}

// ---------------- kernel 2: bucket-region assignment (block scan + global cursor) ----------------
__global__ __launch_bounds__(256) void k_offs(const int* __restrict__ deg,
                                              int* __restrict__ offs,
                                              int* __restrict__ cursor) {
    __shared__ int sc[256];
    __shared__ int sbase;
    int t = threadIdx.x;
    int n = blockIdx.x * 256 + t;
    int d = (n < N_NODES) ? deg[n] : 0;
    sc[t] = d;
    __syncthreads();
    for (int off = 1; off < 256; off <<= 1) {   // inclusive Hillis-Steele scan
        int u = (t >= off) ? sc[t - off] : 0;
        __syncthreads();
        sc[t] += u;
        __syncthreads();
    }
    int incl = sc[t];
    if (t == 255) sbase = atomicAdd(cursor, incl);
    __syncthreads();
    if (n < N_NODES) offs[n] = sbase + (incl - d);
}

// ---------------- kernel 3: h16 = bf16(relu(LN(x))*mask)  +  bucket fill (fused) ----------------
__global__ __launch_bounds__(256) void k_hfill(const float* __restrict__ x,
                                               const float* __restrict__ mask,
                                               const float* __restrict__ lnw,
                                               const float* __restrict__ lnb,
                                               const double* __restrict__ stats,
                                               const int* __restrict__ ei,
                                               int* __restrict__ offs,
                                               int* __restrict__ bucket,
                                               unsigned short* __restrict__ h16,
                                               int total4) {
    if (blockIdx.x < H_BLOCKS) {
        double M = (double)N_NODES * (double)D;
        double mean_d = stats[0] / M;
        double var = stats[1] / M - mean_d * mean_d;
        if (var < 0.0) var = 0.0;
        float mean = (float)mean_d;
        float rstd = (float)(1.0 / (sqrt(var) + (double)EPS));
        int tid = blockIdx.x * 256 + threadIdx.x;
        int stride = H_BLOCKS * 256;
        for (int i = tid; i < total4; i += stride) {
            float4 v = ((const float4*)x)[i];
            float4 m = ((const float4*)mask)[i];
            int c4 = i & (D / 4 - 1);
            float4 w = ((const float4*)lnw)[c4];
            float4 b = ((const float4*)lnb)[c4];
            float4 r;
            r.x = fmaxf((v.x - mean) * rstd * w.x + b.x, 0.f) * m.x;
            r.y = fmaxf((v.y - mean) * rstd * w.y + b.y, 0.f) * m.y;
            r.z = fmaxf((v.z - mean) * rstd * w.z + b.z, 0.f) * m.z;
            r.w = fmaxf((v.w - mean) * rstd * w.w + b.w, 0.f) * m.w;
            ushort4 o;
            o.x = f2bf(r.x); o.y = f2bf(r.y); o.z = f2bf(r.z); o.w = f2bf(r.w);
            ((ushort4*)h16)[i] = o;
        }
    } else {
        int e = (blockIdx.x - H_BLOCKS) * 256 + threadIdx.x;
        if (e < N_EDGES) {
            int dst = ei[N_EDGES + e];
            int p = atomicAdd(offs + dst, 1);
            bucket[p] = ei[e];
        }
    }
}

// ---------------- kernel 4: pull aggregation (atomic-free, bf16 in/out) ----------------
// 32 lanes per dst node, 4 bf16 channels (8B) per lane; f32 accumulate, bf16 store.
__global__ __launch_bounds__(256) void k_agg(const int* __restrict__ bucket,
                                             const int* __restrict__ offs,
                                             const int* __restrict__ deg,
                                             const unsigned short* __restrict__ h16,
                                             unsigned short* __restrict__ agg16) {
    int t = blockIdx.x * blockDim.x + threadIdx.x;
    int node = t >> 5;
    if (node >= N_NODES) return;
    int c = t & 31;
    int dg = deg[node];
    int end = offs[node];          // post-fill value = bucket end
    int start = end - dg;
    float4 acc = {0.f, 0.f, 0.f, 0.f};
    for (int j = start; j < end; ++j) {
        int src = bucket[j];
        uint2 u = *(const uint2*)(h16 + (long long)src * D + c * 4);
        acc.x += __uint_as_float(u.x << 16);
        acc.y += __uint_as_float(u.x & 0xFFFF0000u);
        acc.z += __uint_as_float(u.y << 16);
        acc.w += __uint_as_float(u.y & 0xFFFF0000u);
    }
    float inv = 1.0f / fmaxf((float)dg, 1.0f);
    ushort4 o;
    o.x = f2bf(acc.x * inv); o.y = f2bf(acc.y * inv);
    o.z = f2bf(acc.z * inv); o.w = f2bf(acc.w * inv);
    *(ushort4*)(agg16 + (long long)node * D + c * 4) = o;
}

// ---------------- kernel 5: MFMA dual matvec, LDS-staged fragment-ordered weights ----------------
// 391 blocks x 512 thr (8 waves); wave = ONE node-tile x all 8 out-tiles.
// acc[8] = 32 VGPR (round-10 spilled at 16 accs / 128-VGPR cap -> 460 MB scratch).
// Per phase: linear memcpy of that phase's 64 KB frag block into LDS; B reads are
// ds_read_b128 at (frag*1024 + lane*16) -> fully linear, zero bank conflicts
// (round 10's swizzled layout: 1.05M conflicts). MFMA operand values identical
// to round-8 HW-verified kernel.
__global__ __launch_bounds__(512, 4) void k_mmf(const unsigned short* __restrict__ agg16,
                                                const unsigned short* __restrict__ h16,
                                                const unsigned short* __restrict__ w16f,
                                                const float* __restrict__ b_l,
                                                float* __restrict__ out) {
    __shared__ uint4 lds4[4096];                 // 64 KB: one phase's 64 frags x 1 KB
    const unsigned char* ldsb = (const unsigned char*)lds4;
    int tid  = threadIdx.x;
    int wave = tid >> 6;
    int lane = tid & 63;
    int rc = lane & 15;                          // A-row / B-col / D-col
    int kg = lane >> 4;                          // k-group 0..3
    int slot = blockIdx.x * 8 + wave;            // 0..3127
    bool valid = (slot < MM_TILES);
    int nt = valid ? slot : (MM_TILES - 1);

    f32x4 acc[8];
#pragma unroll
    for (int ot = 0; ot < 8; ++ot) acc[ot] = {0.f, 0.f, 0.f, 0.f};

#pragma unroll
    for (int phase = 0; phase < 2; ++phase) {
        if (phase) __syncthreads();              // all waves done reading prev stage
        {   // stage 64 KB linear (4096 uint4, 8 per thread)
            const uint4* src = (const uint4*)(w16f + phase * 32768);
#pragma unroll
            for (int i = 0; i < 8; ++i)
                lds4[i * 512 + tid] = src[i * 512 + tid];
        }
        __syncthreads();

        const unsigned short* abase = phase ? h16 : agg16;
        const unsigned short* pa = abase + (long long)(nt * 16 + rc) * D + kg * 8;
        const unsigned char* lp = ldsb + lane * 16;

#pragma unroll
        for (int k0 = 0; k0 < 4; ++k0) {
            short8v a = *(const short8v*)(pa + k0 * 32);
#pragma unroll
            for (int ot = 0; ot < 8; ++ot) {
                short8v bhi = *(const short8v*)(lp + (ot * 4 + k0) * 1024);          // s=0
                short8v blo = *(const short8v*)(lp + 32768 + (ot * 4 + k0) * 1024);  // s=1
                acc[ot] = __builtin_amdgcn_mfma_f32_16x16x32_bf16(a, bhi, acc[ot], 0, 0, 0);
                acc[ot] = __builtin_amdgcn_mfma_f32_16x16x32_bf16(a, blo, acc[ot], 0, 0, 0);
            }
        }
    }

    // epilogue: D col=lane&15, row=(lane>>4)*4+r (HW-verified round 8)
    if (valid) {
#pragma unroll
        for (int ot = 0; ot < 8; ++ot) {
            float bias = b_l[ot * 16 + rc];
            float* op = out + (long long)(nt * 16 + kg * 4) * D + ot * 16 + rc;
#pragma unroll
            for (int r = 0; r < 4; ++r) op[(long long)r * D] = acc[ot][r] + bias;
        }
    }
}

// ---------------- launcher ----------------
extern "C" void kernel_launch(void* const* d_in, const int* in_sizes, int n_in,
                              void* d_out, int out_size, void* d_ws, size_t ws_size,
                              hipStream_t stream) {
    const float* x    = (const float*)d_in[0];
    const int*   ei   = (const int*)d_in[1];
    const float* mask = (const float*)d_in[2];
    const float* lnw  = (const float*)d_in[3];
    const float* lnb  = (const float*)d_in[4];
    const float* w_l  = (const float*)d_in[5];
    const float* b_l  = (const float*)d_in[6];
    const float* w_r  = (const float*)d_in[7];
    float* out = (float*)d_out;

    char* ws = (char*)d_ws;
    double* stats = (double*)(ws + WS_STATS_OFF);
    int*    cursor= (int*)(ws + WS_CUR_OFF);
    int*    deg   = (int*)(ws + WS_DEG_OFF);
    int*    offs  = (int*)(ws + WS_OFFS_OFF);
    int*    bucket= (int*)(ws + WS_BUCKET_OFF);
    unsigned short* w16f  = (unsigned short*)(ws + WS_W16F_OFF);
    unsigned short* agg16 = (unsigned short*)(ws + WS_AGG_OFF);
    unsigned short* h16   = (unsigned short*)(ws + WS_H_OFF);

    // zero stats + cursor + deg (ws is poisoned 0xAA before every launch)
    hipMemsetAsync(d_ws, 0, WS_ZERO_BYTES, stream);

    int total4 = N_NODES * D / 4;
    k_pre<<<RED_BLOCKS + DEG_BLOCKS, 256, 0, stream>>>(x, ei, stats, deg, total4);
    k_wprep<<<16, 256, 0, stream>>>(w_l, w_r, w16f);
    k_offs<<<(N_NODES + 255) / 256, 256, 0, stream>>>(deg, offs, cursor);
    k_hfill<<<H_BLOCKS + FILL_BLOCKS, 256, 0, stream>>>(x, mask, lnw, lnb, stats,
                                                        ei, offs, bucket, h16, total4);
    int ablocks = (N_NODES * 32 + 255) / 256;   // 6250
    k_agg<<<ablocks, 256, 0, stream>>>(bucket, offs, deg, h16, agg16);
    k_mmf<<<MM_BLOCKS, 512, 0, stream>>>(agg16, h16, w16f, b_l, out);
}